// Round 5
// baseline (247.866 us; speedup 1.0000x reference)
//
#include <hip/hip_runtime.h>

typedef _Float16 half2v __attribute__((ext_vector_type(2)));
typedef _Float16 half4v __attribute__((ext_vector_type(4)));
typedef _Float16 half8v __attribute__((ext_vector_type(8)));
typedef float f32x4 __attribute__((ext_vector_type(4)));

// ---- fused front-end: dw3x3 (VALU) + pw1x1/red1x1 (MFMA) + BN partials ----
// 8x8 px tile, 1024 blocks (4/CU), 4 waves. q-loop barrier-free (wave-private
// s_in4[w]); one block barrier before the MFMA phase. Weight A-fragments
// loaded once per block. NO global atomics: each block writes its 32 BN
// partial sums to its own slot partial[blk][32] (k_red reduces them).
//   h16[b][g][y][x][4cg]  (D-frag rr=0..3 = one cg group -> one 8B store)
//   r16[b][y][x][16ch]    (k_main reads all 16 ch as 2x16B)
__launch_bounds__(256, 4)
__global__ void k_front(const float* __restrict__ in, const float* __restrict__ wdw,
                        const float* __restrict__ wpw, const float* __restrict__ wred,
                        const float* __restrict__ wspan,
                        _Float16* __restrict__ h16, _Float16* __restrict__ r16,
                        float* __restrict__ partial, _Float16* __restrict__ w16){
  __shared__ float4 s_in4[4][10][12];              // [wave][ry][rx] 4ch contiguous
  __shared__ __attribute__((aligned(16))) _Float16 s_dwh[64][72];  // [px][c]
  __shared__ __attribute__((aligned(16))) _Float16 s_cvh[64][72];  // [px][c]
  __shared__ float s_red[4][32];
  int t = threadIdx.x;
  int w = t >> 6, lane = t & 63;
  int lx = lane & 7, ly = lane >> 3;
  int c15 = lane & 15, hi = lane >> 4;
  int blk0 = blockIdx.x;

  // fold prep: w_span fp32 -> fp16 (12544 elems, blocks 0..48)
  {
    int i = blk0 * 256 + t;
    if (i < 12544) w16[i] = (_Float16)wspan[i];
  }

  int blk = ((blk0 & 7) << 7) | (blk0 >> 3);       // XCD-contiguous remap (bijective)
  int tile = blk & 255, b = blk >> 8;
  int x0 = (tile & 15) << 3, y0 = (tile >> 4) << 3;
  const float* inb = in + ((long)b << 20) + ((long)(w << 2) << 14);

  // ---- A-fragments loaded once: pw rows 16w..16w+15, red rows 0..15 ----
  const float* ap = wpw + (((w << 4) + c15) << 6) + (hi << 3);
  float4 ap0 = *(const float4*)(ap);
  float4 ap1 = *(const float4*)(ap + 4);
  float4 ap2 = *(const float4*)(ap + 32);
  float4 ap3 = *(const float4*)(ap + 36);
  const float* arp = wred + (c15 << 6) + (hi << 3);
  float4 ar0 = *(const float4*)(arp);
  float4 ar1 = *(const float4*)(arp + 4);
  float4 ar2 = *(const float4*)(arp + 32);
  float4 ar3 = *(const float4*)(arp + 36);
  half8v a_pw0 = {(_Float16)ap0.x,(_Float16)ap0.y,(_Float16)ap0.z,(_Float16)ap0.w,
                  (_Float16)ap1.x,(_Float16)ap1.y,(_Float16)ap1.z,(_Float16)ap1.w};
  half8v a_pw1 = {(_Float16)ap2.x,(_Float16)ap2.y,(_Float16)ap2.z,(_Float16)ap2.w,
                  (_Float16)ap3.x,(_Float16)ap3.y,(_Float16)ap3.z,(_Float16)ap3.w};
  half8v a_rd0 = {(_Float16)ar0.x,(_Float16)ar0.y,(_Float16)ar0.z,(_Float16)ar0.w,
                  (_Float16)ar1.x,(_Float16)ar1.y,(_Float16)ar1.z,(_Float16)ar1.w};
  half8v a_rd1 = {(_Float16)ar2.x,(_Float16)ar2.y,(_Float16)ar2.z,(_Float16)ar2.w,
                  (_Float16)ar3.x,(_Float16)ar3.y,(_Float16)ar3.z,(_Float16)ar3.w};

  // ---- per-wave halo staging: wave w owns channel group w; 100 pts, 2/lane ----
  int p1 = lane + 64;
  int ry0 = lane / 10, rx0 = lane - ry0 * 10;
  int ry1 = p1 / 10,   rx1 = p1 - ry1 * 10;
  int yy0 = y0 + ry0 - 1, xx0 = x0 + rx0 - 1;
  int yy1 = y0 + ry1 - 1, xx1 = x0 + rx1 - 1;
  bool ok0 = (unsigned)yy0 < 128u && (unsigned)xx0 < 128u;
  bool ok1 = (p1 < 100) && ((unsigned)yy1 < 128u) && ((unsigned)xx1 < 128u);
  int o0 = (yy0 << 7) + xx0, o1 = (yy1 << 7) + xx1;

  float4 v0 = make_float4(0.f,0.f,0.f,0.f), v1 = make_float4(0.f,0.f,0.f,0.f);
  if (ok0){ v0.x = inb[o0]; v0.y = inb[o0+16384]; v0.z = inb[o0+32768]; v0.w = inb[o0+49152]; }
  if (ok1){ v1.x = inb[o1]; v1.y = inb[o1+16384]; v1.z = inb[o1+32768]; v1.w = inb[o1+49152]; }

  for (int q = 0; q < 4; q++){
    s_in4[w][ry0][rx0] = v0;
    if (p1 < 100) s_in4[w][ry1][rx1] = v1;
    __builtin_amdgcn_wave_barrier();               // keep dw reads after these writes

    if (q < 3){                                    // prefetch q+1; hides under dw
      const float* pq = inb + ((long)(q + 1) << 18);
      v0 = make_float4(0.f,0.f,0.f,0.f); v1 = make_float4(0.f,0.f,0.f,0.f);
      if (ok0){ v0.x = pq[o0]; v0.y = pq[o0+16384]; v0.z = pq[o0+32768]; v0.w = pq[o0+49152]; }
      if (ok1){ v1.x = pq[o1]; v1.y = pq[o1+16384]; v1.z = pq[o1+32768]; v1.w = pq[o1+49152]; }
    }

    int wdbase = __builtin_amdgcn_readfirstlane(((q << 4) + (w << 2)) * 9);
    const float* wd = wdw + wdbase;                // forced scalar path
    float4 a = make_float4(0.f,0.f,0.f,0.f);
    float4 cv = make_float4(0.f,0.f,0.f,0.f);
    #pragma unroll
    for (int dy = 0; dy < 3; dy++){
      #pragma unroll
      for (int dx = 0; dx < 3; dx++){
        float4 v = s_in4[w][ly + dy][lx + dx];
        int k = dy * 3 + dx;
        a.x += v.x * wd[k];
        a.y += v.y * wd[9 + k];
        a.z += v.z * wd[18 + k];
        a.w += v.w * wd[27 + k];
        if (k == 4) cv = v;
      }
    }
    int cb = (q << 4) + (w << 2);
    half4v ah = {(_Float16)a.x,(_Float16)a.y,(_Float16)a.z,(_Float16)a.w};
    half4v eh = {(_Float16)cv.x,(_Float16)cv.y,(_Float16)cv.z,(_Float16)cv.w};
    *(half4v*)&s_dwh[lane][cb] = ah;
    *(half4v*)&s_cvh[lane][cb] = eh;
  }

  __syncthreads();                                 // all 64 channels deposited

  // ---- pw GEMM: wave w -> o-rows 16w..16w+15, 64 px, K=64 (8 MFMAs) ----
  f32x4 z = {0.f,0.f,0.f,0.f};
  f32x4 acc[4] = {z, z, z, z};
  #pragma unroll
  for (int tt = 0; tt < 4; tt++){
    half8v b0 = *(const half8v*)&s_dwh[(tt << 4) + c15][hi << 3];
    half8v b1 = *(const half8v*)&s_dwh[(tt << 4) + c15][32 + (hi << 3)];
    acc[tt] = __builtin_amdgcn_mfma_f32_16x16x32_f16(a_pw0, b0, acc[tt], 0, 0, 0);
    acc[tt] = __builtin_amdgcn_mfma_f32_16x16x32_f16(a_pw1, b1, acc[tt], 0, 0, 0);
  }
  // D: ch = 16w+4hi+rr (4 consecutive = group g=4w+hi), col px = 16tt+c15
  #pragma unroll
  for (int tt = 0; tt < 4; tt++){
    int px = (tt << 4) + c15;
    int pyl = px >> 3, pxl = px & 7;
    int gout = (w << 2) + hi;
    long off = ((((long)((b << 4) + gout)) << 14) + ((y0 + pyl) << 7) + x0 + pxl) << 2;
    half4v hv = {(_Float16)acc[tt][0], (_Float16)acc[tt][1],
                 (_Float16)acc[tt][2], (_Float16)acc[tt][3]};
    *(half4v*)&h16[off] = hv;
  }

  // ---- red GEMM: wave w -> px-tile w (16 ch x 16 px, K=64) = 2 MFMAs ----
  f32x4 rac = z;
  {
    half8v b0 = *(const half8v*)&s_cvh[(w << 4) + c15][hi << 3];
    half8v b1 = *(const half8v*)&s_cvh[(w << 4) + c15][32 + (hi << 3)];
    rac = __builtin_amdgcn_mfma_f32_16x16x32_f16(a_rd0, b0, rac, 0, 0, 0);
    rac = __builtin_amdgcn_mfma_f32_16x16x32_f16(a_rd1, b1, rac, 0, 0, 0);
  }
  {
    int px = (w << 4) + c15;
    int pyl = px >> 3, pxl = px & 7;
    long roff = ((((long)b << 14) + ((y0 + pyl) << 7) + x0 + pxl) << 4) + (hi << 2);
    half4v rv4 = {(_Float16)rac[0], (_Float16)rac[1], (_Float16)rac[2], (_Float16)rac[3]};
    *(half4v*)&r16[roff] = rv4;
  }

  // ---- BN partials: wave-reduce over 16 px, combine waves, ONE 128B store ----
  #pragma unroll
  for (int rr = 0; rr < 4; rr++){
    float v = rac[rr], s2 = v * v;
    #pragma unroll
    for (int m = 1; m < 16; m <<= 1){
      v  += __shfl_xor(v,  m, 64);
      s2 += __shfl_xor(s2, m, 64);
    }
    if (c15 == 0){
      int ch = (hi << 2) + rr;
      s_red[w][2 * ch]     = v;
      s_red[w][2 * ch + 1] = s2;
    }
  }
  __syncthreads();
  if (t < 32)
    partial[(blk0 << 5) + t] = s_red[0][t] + s_red[1][t] + s_red[2][t] + s_red[3][t];
}

// ---- reduce 1024 BN partial slots -> finalized scale/bias sb[32] ----
__global__ void k_red(const float* __restrict__ partial, const float* __restrict__ gamma,
                      const float* __restrict__ beta, float* __restrict__ sb){
  __shared__ float sp[1024];
  int t = threadIdx.x;
  int c = t & 31, grp = t >> 5;                    // 32 groups x 32 stat-slots
  float s = 0.f;
  #pragma unroll 4
  for (int i = grp; i < 1024; i += 32) s += partial[(i << 5) + c];
  sp[t] = s;
  __syncthreads();
  if (t < 32){
    float v = 0.f;
    #pragma unroll
    for (int k = 0; k < 32; k++) v += sp[(k << 5) + t];
    sp[t] = v;                                     // columns disjoint -> safe
  }
  __syncthreads();
  if (t < 16){
    const float inv_n = 1.52587890625e-5f;         // 1/65536 (exact)
    float mean = sp[2 * t] * inv_n;
    float var  = sp[2 * t + 1] * inv_n - mean * mean;
    float inv  = rsqrtf(var + 1e-5f);
    float sc   = gamma[t] * inv;
    sb[2 * t]     = sc;
    sb[2 * t + 1] = beta[t] - mean * sc;
  }
}

// ---- main involution: 2 adjacent tiles per block (A,B), sb precomputed ----
// Unit B's halo loads are issued before barrier1 -> latency amortized over
// unit A's ~1700-cycle compute. A-stores deferred to kernel end (no barrier
// pays a store drain). 2048 blocks, >=6 blocks/CU pinned.
__launch_bounds__(256, 6)
__global__ void k_main(const _Float16* __restrict__ h16, const _Float16* __restrict__ r16,
                       const float* __restrict__ sb, const _Float16* __restrict__ w16,
                       float* __restrict__ out){
  __shared__ float4 s_h4[22][24];                  // halo [row][col] fp32
  int t = threadIdx.x;
  int g = blockIdx.y, b = blockIdx.z;
  int t0 = blockIdx.x << 1;                        // tiles t0 (A), t0+1 (B): same row
  int ltx = t & 15, lty = t >> 4;
  int txA = (t0 & 7) << 4, ty0 = (t0 >> 3) << 4;
  int txB = txA + 16;
  int pxA = txA + ltx, py = ty0 + lty;

  // r loads for both units, issued first
  const _Float16* rpA = r16 + ((((long)b << 14) + (py << 7) + pxA) << 4);
  half8v raA = *(const half8v*)rpA,         rbA = *(const half8v*)(rpA + 8);
  half8v raB = *(const half8v*)(rpA + 256), rbB = *(const half8v*)(rpA + 264);

  // halo geometry (484 pts: t and t+256)
  const _Float16* hp = h16 + (((long)((b << 4) + g)) << 16);
  int p1 = t + 256;
  int ry0 = t / 22,  rx0 = t - ry0 * 22;
  int ry1 = p1 / 22, rx1 = p1 - ry1 * 22;
  int yy0 = ty0 + ry0 - 3, yy1 = ty0 + ry1 - 3;
  bool oky0 = (unsigned)yy0 < 128u;
  bool oky1 = (p1 < 484) && ((unsigned)yy1 < 128u);
  int xA0 = txA + rx0 - 3, xA1 = txA + rx1 - 3;

  // halo A loads, then halo B loads (B stays in flight into compute A)
  half4v hA0 = {0,0,0,0}, hA1 = {0,0,0,0}, hB0 = {0,0,0,0}, hB1 = {0,0,0,0};
  if (oky0 && (unsigned)xA0 < 128u) hA0 = *(const half4v*)&hp[(long)(((yy0 << 7) + xA0) << 2)];
  if (oky1 && (unsigned)xA1 < 128u) hA1 = *(const half4v*)&hp[(long)(((yy1 << 7) + xA1) << 2)];
  if (oky0 && (unsigned)(xA0 + 16) < 128u) hB0 = *(const half4v*)&hp[(long)(((yy0 << 7) + xA0 + 16) << 2)];
  if (oky1 && (unsigned)(xA1 + 16) < 128u) hB1 = *(const half4v*)&hp[(long)(((yy1 << 7) + xA1 + 16) << 2)];

  // ds_write A (waits only on hA via counted vmcnt; hB stays outstanding)
  s_h4[ry0][rx0] = make_float4((float)hA0[0], (float)hA0[1], (float)hA0[2], (float)hA0[3]);
  if (p1 < 484)
    s_h4[ry1][rx1] = make_float4((float)hA1[0], (float)hA1[1], (float)hA1[2], (float)hA1[3]);

  // BN scale/bias: uniform scalar loads (no LDS, no barrier dependency)
  float scl[16], ofs[16];
  #pragma unroll
  for (int c = 0; c < 16; c++){ scl[c] = sb[2 * c]; ofs[c] = sb[2 * c + 1]; }

  // pack rv for unit A while loads drain
  half2v rvA[8], rvB[8];
  #pragma unroll
  for (int j = 0; j < 8; j++){
    float v0 = fmaxf((float)raA[j] * scl[j]     + ofs[j],     0.f);
    float v1 = fmaxf((float)rbA[j] * scl[j + 8] + ofs[j + 8], 0.f);
    // rv order: channels 0..15 -> pairs (2j,2j+1); raA holds ch 0..7, rbA 8..15
    (void)v0; (void)v1;
  }
  {
    float rv[16];
    #pragma unroll
    for (int c = 0; c < 8; c++){
      rv[c]     = fmaxf((float)raA[c] * scl[c]     + ofs[c],     0.f);
      rv[c + 8] = fmaxf((float)rbA[c] * scl[c + 8] + ofs[c + 8], 0.f);
    }
    #pragma unroll
    for (int j = 0; j < 8; j++){
      half2v pk; pk[0] = (_Float16)rv[2 * j]; pk[1] = (_Float16)rv[2 * j + 1];
      rvA[j] = pk;
    }
  }

  const _Float16* wg = w16 + g * 784;              // uniform -> scalar pipe
  const half2v* wg2 = (const half2v*)wg;

  float aA0 = 0.f, aA1 = 0.f, aA2 = 0.f, aA3 = 0.f;
  float aB0 = 0.f, aB1 = 0.f, aB2 = 0.f, aB3 = 0.f;

  auto run49 = [&](const half2v (&rv2)[8], float& a0, float& a1, float& a2, float& a3){
    #pragma unroll
    for (int kh = 0; kh < 7; kh++){
      #pragma unroll
      for (int kw = 0; kw < 7; kw++){
        int k = kh * 7 + kw;
        float kv0 = 0.f, kv1 = 0.f;                // split dep chain (2x4 deep)
#if __has_builtin(__builtin_amdgcn_fdot2)
        #pragma unroll
        for (int j = 0; j < 4; j++){
          kv0 = __builtin_amdgcn_fdot2(rv2[j],     wg2[k * 8 + j],     kv0, false);
          kv1 = __builtin_amdgcn_fdot2(rv2[j + 4], wg2[k * 8 + j + 4], kv1, false);
        }
#else
        #pragma unroll
        for (int j = 0; j < 4; j++){
          kv0 += (float)rv2[j][0]     * (float)wg2[k * 8 + j][0]
               + (float)rv2[j][1]     * (float)wg2[k * 8 + j][1];
          kv1 += (float)rv2[j + 4][0] * (float)wg2[k * 8 + j + 4][0]
               + (float)rv2[j + 4][1] * (float)wg2[k * 8 + j + 4][1];
        }
#endif
        float kv = kv0 + kv1;
        float4 hv = s_h4[lty + kh][ltx + kw];
        a0 += kv * hv.x;
        a1 += kv * hv.y;
        a2 += kv * hv.z;
        a3 += kv * hv.w;
      }
    }
  };

  __syncthreads();                                 // s_h4(A) ready
  run49(rvA, aA0, aA1, aA2, aA3);
  __syncthreads();                                 // all done reading s_h4(A)

  // ds_write B (hB long since landed under compute A)
  s_h4[ry0][rx0] = make_float4((float)hB0[0], (float)hB0[1], (float)hB0[2], (float)hB0[3]);
  if (p1 < 484)
    s_h4[ry1][rx1] = make_float4((float)hB1[0], (float)hB1[1], (float)hB1[2], (float)hB1[3]);

  {
    float rv[16];
    #pragma unroll
    for (int c = 0; c < 8; c++){
      rv[c]     = fmaxf((float)raB[c] * scl[c]     + ofs[c],     0.f);
      rv[c + 8] = fmaxf((float)rbB[c] * scl[c + 8] + ofs[c + 8], 0.f);
    }
    #pragma unroll
    for (int j = 0; j < 8; j++){
      half2v pk; pk[0] = (_Float16)rv[2 * j]; pk[1] = (_Float16)rv[2 * j + 1];
      rvB[j] = pk;
    }
  }

  __syncthreads();                                 // s_h4(B) ready
  run49(rvB, aB0, aB1, aB2, aB3);

  // deferred stores (no barrier after -> no drain cost)
  long obA = (((long)((b << 6) + (g << 2))) << 14) + (py << 7) + pxA;
  out[obA]         = aA0;
  out[obA + 16384] = aA1;
  out[obA + 32768] = aA2;
  out[obA + 49152] = aA3;
  long obB = obA + 16;
  out[obB]         = aB0;
  out[obB + 16384] = aB1;
  out[obB + 32768] = aB2;
  out[obB + 49152] = aB3;
}

extern "C" void kernel_launch(void* const* d_in, const int* in_sizes, int n_in,
                              void* d_out, int out_size, void* d_ws, size_t ws_size,
                              hipStream_t stream){
  const float* in       = (const float*)d_in[0];
  const float* w_dw     = (const float*)d_in[1];
  const float* w_pw     = (const float*)d_in[2];
  const float* gamma    = (const float*)d_in[3];
  const float* beta     = (const float*)d_in[4];
  const float* w_reduce = (const float*)d_in[5];
  const float* w_span   = (const float*)d_in[6];
  float* out = (float*)d_out;

  _Float16* h16 = (_Float16*)d_ws;                 // 4194304 halfs (8 MB)
  _Float16* r16 = h16 + 4194304;                   // 1048576 halfs (2 MB)
  _Float16* w16 = r16 + 1048576;                   // 12544 halfs (pad to 16384)
  float* partial = (float*)(w16 + 16384);          // 1024*32 floats (128 KB)
  float* sb      = partial + 32768;                // 32 floats

  k_front<<<1024, 256, 0, stream>>>(in, w_dw, w_pw, w_reduce, w_span,
                                    h16, r16, partial, w16);
  k_red  <<<1, 1024, 0, stream>>>(partial, gamma, beta, sb);
  dim3 grid(32, 16, 4);
  k_main <<<grid, 256, 0, stream>>>(h16, r16, sb, w16, out);
}

// Round 6
// 122.755 us; speedup vs baseline: 2.0192x; 2.0192x over previous
//
#include <hip/hip_runtime.h>

typedef _Float16 half2v __attribute__((ext_vector_type(2)));
typedef _Float16 half4v __attribute__((ext_vector_type(4)));
typedef _Float16 half8v __attribute__((ext_vector_type(8)));
typedef float f32x4 __attribute__((ext_vector_type(4)));

// ---- fused front-end: dw3x3 (VALU) + pw1x1/red1x1 (MFMA) + BN partials ----
// 8x8 px tile, 1024 blocks (4/CU), 4 waves. q-loop barrier-free (wave-private
// s_in4[w]); 2-DEEP register prefetch (q+2 issued before dw(q)) so the LDS
// commit at loop top never waits on global latency. One block barrier before
// the MFMA phase. No atomics: 32 BN partials per block -> partial[blk][32].
//   h16[b][g][y][x][4cg]  (D-frag rr=0..3 = one cg group -> one 8B store)
//   r16[b][y][x][16ch]    (k_main reads all 16 ch as 2x16B)
__launch_bounds__(256, 4)
__global__ void k_front(const float* __restrict__ in, const float* __restrict__ wdw,
                        const float* __restrict__ wpw, const float* __restrict__ wred,
                        _Float16* __restrict__ h16, _Float16* __restrict__ r16,
                        float* __restrict__ partial){
  __shared__ float4 s_in4[4][10][12];              // [wave][ry][rx] 4ch contiguous
  __shared__ __attribute__((aligned(16))) _Float16 s_dwh[64][72];  // [px][c]
  __shared__ __attribute__((aligned(16))) _Float16 s_cvh[64][72];  // [px][c]
  __shared__ float s_red[4][32];
  int t = threadIdx.x;
  int w = t >> 6, lane = t & 63;
  int lx = lane & 7, ly = lane >> 3;
  int c15 = lane & 15, hi = lane >> 4;
  int blk0 = blockIdx.x;

  int blk = ((blk0 & 7) << 7) | (blk0 >> 3);       // XCD-contiguous remap (bijective)
  int tile = blk & 255, b = blk >> 8;
  int x0 = (tile & 15) << 3, y0 = (tile >> 4) << 3;
  const float* inb = in + ((long)b << 20) + ((long)(w << 2) << 14);

  // ---- A-fragments loaded once: pw rows 16w..16w+15, red rows 0..15 ----
  const float* ap = wpw + (((w << 4) + c15) << 6) + (hi << 3);
  float4 ap0 = *(const float4*)(ap);
  float4 ap1 = *(const float4*)(ap + 4);
  float4 ap2 = *(const float4*)(ap + 32);
  float4 ap3 = *(const float4*)(ap + 36);
  const float* arp = wred + (c15 << 6) + (hi << 3);
  float4 ar0 = *(const float4*)(arp);
  float4 ar1 = *(const float4*)(arp + 4);
  float4 ar2 = *(const float4*)(arp + 32);
  float4 ar3 = *(const float4*)(arp + 36);
  half8v a_pw0 = {(_Float16)ap0.x,(_Float16)ap0.y,(_Float16)ap0.z,(_Float16)ap0.w,
                  (_Float16)ap1.x,(_Float16)ap1.y,(_Float16)ap1.z,(_Float16)ap1.w};
  half8v a_pw1 = {(_Float16)ap2.x,(_Float16)ap2.y,(_Float16)ap2.z,(_Float16)ap2.w,
                  (_Float16)ap3.x,(_Float16)ap3.y,(_Float16)ap3.z,(_Float16)ap3.w};
  half8v a_rd0 = {(_Float16)ar0.x,(_Float16)ar0.y,(_Float16)ar0.z,(_Float16)ar0.w,
                  (_Float16)ar1.x,(_Float16)ar1.y,(_Float16)ar1.z,(_Float16)ar1.w};
  half8v a_rd1 = {(_Float16)ar2.x,(_Float16)ar2.y,(_Float16)ar2.z,(_Float16)ar2.w,
                  (_Float16)ar3.x,(_Float16)ar3.y,(_Float16)ar3.z,(_Float16)ar3.w};

  // ---- per-wave halo staging: wave w owns channel group w; 100 pts, 2/lane ----
  int p1 = lane + 64;
  int ry0 = lane / 10, rx0 = lane - ry0 * 10;
  int ry1 = p1 / 10,   rx1 = p1 - ry1 * 10;
  int yy0 = y0 + ry0 - 1, xx0 = x0 + rx0 - 1;
  int yy1 = y0 + ry1 - 1, xx1 = x0 + rx1 - 1;
  bool ok0 = (unsigned)yy0 < 128u && (unsigned)xx0 < 128u;
  bool ok1 = (p1 < 100) && ((unsigned)yy1 < 128u) && ((unsigned)xx1 < 128u);
  int o0 = (yy0 << 7) + xx0, o1 = (yy1 << 7) + xx1;

  // dw conv + fp16 deposit for chunk q (reads wave-private s_in4[w])
  auto dw_dep = [&](int q){
    int wdbase = __builtin_amdgcn_readfirstlane(((q << 4) + (w << 2)) * 9);
    const float* wd = wdw + wdbase;                // forced scalar path
    float4 a = make_float4(0.f,0.f,0.f,0.f);
    float4 cv = make_float4(0.f,0.f,0.f,0.f);
    #pragma unroll
    for (int dy = 0; dy < 3; dy++){
      #pragma unroll
      for (int dx = 0; dx < 3; dx++){
        float4 v = s_in4[w][ly + dy][lx + dx];
        int k = dy * 3 + dx;
        a.x += v.x * wd[k];
        a.y += v.y * wd[9 + k];
        a.z += v.z * wd[18 + k];
        a.w += v.w * wd[27 + k];
        if (k == 4) cv = v;
      }
    }
    int cb = (q << 4) + (w << 2);
    half4v ah = {(_Float16)a.x,(_Float16)a.y,(_Float16)a.z,(_Float16)a.w};
    half4v eh = {(_Float16)cv.x,(_Float16)cv.y,(_Float16)cv.z,(_Float16)cv.w};
    *(half4v*)&s_dwh[lane][cb] = ah;
    *(half4v*)&s_cvh[lane][cb] = eh;
  };

  // 2-deep prologue: q=0 -> buffer A, q=1 -> buffer B
  float4 vA0 = make_float4(0.f,0.f,0.f,0.f), vA1 = vA0, vB0 = vA0, vB1 = vA0;
  if (ok0){ vA0.x = inb[o0]; vA0.y = inb[o0+16384]; vA0.z = inb[o0+32768]; vA0.w = inb[o0+49152]; }
  if (ok1){ vA1.x = inb[o1]; vA1.y = inb[o1+16384]; vA1.z = inb[o1+32768]; vA1.w = inb[o1+49152]; }
  {
    const float* p1q = inb + (1L << 18);
    if (ok0){ vB0.x = p1q[o0]; vB0.y = p1q[o0+16384]; vB0.z = p1q[o0+32768]; vB0.w = p1q[o0+49152]; }
    if (ok1){ vB1.x = p1q[o1]; vB1.y = p1q[o1+16384]; vB1.z = p1q[o1+32768]; vB1.w = p1q[o1+49152]; }
  }

  #pragma unroll
  for (int qq = 0; qq < 2; qq++){
    // ---- even q (buffer A): commit, prefetch q+2 into A, compute ----
    s_in4[w][ry0][rx0] = vA0;
    if (p1 < 100) s_in4[w][ry1][rx1] = vA1;
    __builtin_amdgcn_wave_barrier();
    if (qq == 0){
      const float* pq = inb + (2L << 18);
      vA0 = make_float4(0.f,0.f,0.f,0.f); vA1 = vA0;
      if (ok0){ vA0.x = pq[o0]; vA0.y = pq[o0+16384]; vA0.z = pq[o0+32768]; vA0.w = pq[o0+49152]; }
      if (ok1){ vA1.x = pq[o1]; vA1.y = pq[o1+16384]; vA1.z = pq[o1+32768]; vA1.w = pq[o1+49152]; }
    }
    dw_dep(qq << 1);
    __builtin_amdgcn_wave_barrier();               // dw reads before next commit

    // ---- odd q (buffer B): commit, prefetch q+2 into B, compute ----
    s_in4[w][ry0][rx0] = vB0;
    if (p1 < 100) s_in4[w][ry1][rx1] = vB1;
    __builtin_amdgcn_wave_barrier();
    if (qq == 0){
      const float* pq = inb + (3L << 18);
      vB0 = make_float4(0.f,0.f,0.f,0.f); vB1 = vB0;
      if (ok0){ vB0.x = pq[o0]; vB0.y = pq[o0+16384]; vB0.z = pq[o0+32768]; vB0.w = pq[o0+49152]; }
      if (ok1){ vB1.x = pq[o1]; vB1.y = pq[o1+16384]; vB1.z = pq[o1+32768]; vB1.w = pq[o1+49152]; }
    }
    dw_dep((qq << 1) + 1);
    __builtin_amdgcn_wave_barrier();
  }

  __syncthreads();                                 // all 64 channels deposited

  // ---- pw GEMM: wave w -> o-rows 16w..16w+15, 64 px, K=64 (8 MFMAs) ----
  f32x4 z = {0.f,0.f,0.f,0.f};
  f32x4 acc[4] = {z, z, z, z};
  #pragma unroll
  for (int tt = 0; tt < 4; tt++){
    half8v b0 = *(const half8v*)&s_dwh[(tt << 4) + c15][hi << 3];
    half8v b1 = *(const half8v*)&s_dwh[(tt << 4) + c15][32 + (hi << 3)];
    acc[tt] = __builtin_amdgcn_mfma_f32_16x16x32_f16(a_pw0, b0, acc[tt], 0, 0, 0);
    acc[tt] = __builtin_amdgcn_mfma_f32_16x16x32_f16(a_pw1, b1, acc[tt], 0, 0, 0);
  }
  // D: ch = 16w+4hi+rr (4 consecutive = group g=4w+hi), col px = 16tt+c15
  #pragma unroll
  for (int tt = 0; tt < 4; tt++){
    int px = (tt << 4) + c15;
    int pyl = px >> 3, pxl = px & 7;
    int gout = (w << 2) + hi;
    long off = ((((long)((b << 4) + gout)) << 14) + ((y0 + pyl) << 7) + x0 + pxl) << 2;
    half4v hv = {(_Float16)acc[tt][0], (_Float16)acc[tt][1],
                 (_Float16)acc[tt][2], (_Float16)acc[tt][3]};
    *(half4v*)&h16[off] = hv;
  }

  // ---- red GEMM: wave w -> px-tile w (16 ch x 16 px, K=64) = 2 MFMAs ----
  f32x4 rac = z;
  {
    half8v b0 = *(const half8v*)&s_cvh[(w << 4) + c15][hi << 3];
    half8v b1 = *(const half8v*)&s_cvh[(w << 4) + c15][32 + (hi << 3)];
    rac = __builtin_amdgcn_mfma_f32_16x16x32_f16(a_rd0, b0, rac, 0, 0, 0);
    rac = __builtin_amdgcn_mfma_f32_16x16x32_f16(a_rd1, b1, rac, 0, 0, 0);
  }
  {
    int px = (w << 4) + c15;
    int pyl = px >> 3, pxl = px & 7;
    long roff = ((((long)b << 14) + ((y0 + pyl) << 7) + x0 + pxl) << 4) + (hi << 2);
    half4v rv4 = {(_Float16)rac[0], (_Float16)rac[1], (_Float16)rac[2], (_Float16)rac[3]};
    *(half4v*)&r16[roff] = rv4;
  }

  // ---- BN partials: wave-reduce over 16 px, combine waves, ONE 128B store ----
  #pragma unroll
  for (int rr = 0; rr < 4; rr++){
    float v = rac[rr], s2 = v * v;
    #pragma unroll
    for (int m = 1; m < 16; m <<= 1){
      v  += __shfl_xor(v,  m, 64);
      s2 += __shfl_xor(s2, m, 64);
    }
    if (c15 == 0){
      int ch = (hi << 2) + rr;
      s_red[w][2 * ch]     = v;
      s_red[w][2 * ch + 1] = s2;
    }
  }
  __syncthreads();
  if (t < 32)
    partial[(blk0 << 5) + t] = s_red[0][t] + s_red[1][t] + s_red[2][t] + s_red[3][t];
}

// ---- reduce 1024 BN partial slots -> sb[32]; also w_span fp32 -> fp16 ----
__global__ void k_red(const float* __restrict__ partial, const float* __restrict__ gamma,
                      const float* __restrict__ beta, float* __restrict__ sb,
                      const float* __restrict__ wspan, _Float16* __restrict__ w16){
  __shared__ float sp[1024];
  int t = threadIdx.x;
  int c = t & 31, grp = t >> 5;                    // 32 groups x 32 stat-slots
  float s = 0.f;
  #pragma unroll 4
  for (int i = grp; i < 1024; i += 32) s += partial[(i << 5) + c];
  sp[t] = s;
  // w_span conversion on otherwise-idle threads (independent of reduce)
  for (int i = t; i < 12544; i += 1024) w16[i] = (_Float16)wspan[i];
  __syncthreads();
  if (t < 32){
    float v = 0.f;
    #pragma unroll
    for (int k = 0; k < 32; k++) v += sp[(k << 5) + t];
    sp[t] = v;                                     // columns disjoint -> safe
  }
  __syncthreads();
  if (t < 16){
    const float inv_n = 1.52587890625e-5f;         // 1/65536 (exact)
    float mean = sp[2 * t] * inv_n;
    float var  = sp[2 * t + 1] * inv_n - mean * mean;
    float inv  = rsqrtf(var + 1e-5f);
    float sc   = gamma[t] * inv;
    sb[2 * t]     = sc;
    sb[2 * t + 1] = beta[t] - mean * sc;
  }
}

// ---- main involution: per (b, g, 16x16 tile); sb precomputed by k_red ----
__launch_bounds__(256)
__global__ void k_main(const _Float16* __restrict__ h16, const _Float16* __restrict__ r16,
                       const float* __restrict__ sb, const _Float16* __restrict__ w16,
                       float* __restrict__ out){
  __shared__ float4 s_h4[22][24];                  // halo [row][col] fp32
  __shared__ float  s_sb[32];
  int t = threadIdx.x;
  int g = blockIdx.y, b = blockIdx.z;
  int bx = blockIdx.x;
  bx = ((bx & 7) << 3) | (bx >> 3);                // XCD-contiguous remap (bijective)
  int tx0 = (bx & 7) << 4, ty0 = (bx >> 3) << 4;

  int ltx = t & 15, lty = t >> 4;
  int px = tx0 + ltx, py = ty0 + lty;

  // r: all 16 channels contiguous -> 2x16B loads, issued early
  const _Float16* rp = r16 + ((((long)b << 14) + (py << 7) + px) << 4);
  half8v ra = *(const half8v*)rp;
  half8v rb = *(const half8v*)(rp + 8);

  // h halo: one 8B half4 load per point (4 cg channels contiguous)
  const _Float16* hp = h16 + (((long)((b << 4) + g)) << 16);
  for (int p = t; p < 484; p += 256){              // 22x22 halo points
    int ry = p / 22, rx = p - ry * 22;
    int yy = ty0 + ry - 3, xx = tx0 + rx - 3;
    float4 v = make_float4(0.f,0.f,0.f,0.f);
    if ((unsigned)yy < 128u && (unsigned)xx < 128u){
      half4v hh = *(const half4v*)&hp[(long)(((yy << 7) + xx) << 2)];
      v = make_float4((float)hh[0], (float)hh[1], (float)hh[2], (float)hh[3]);
    }
    s_h4[ry][rx] = v;
  }
  if (t < 32) s_sb[t] = sb[t];
  __syncthreads();

  float rv[16];
  #pragma unroll
  for (int c = 0; c < 8; c++){
    rv[c]     = fmaxf((float)ra[c] * s_sb[2*c]     + s_sb[2*c+1],     0.f);
    rv[c + 8] = fmaxf((float)rb[c] * s_sb[2*(c+8)] + s_sb[2*(c+8)+1], 0.f);
  }
#if __has_builtin(__builtin_amdgcn_fdot2)
  half2v rv2[8];
  #pragma unroll
  for (int j = 0; j < 8; j++){
    half2v pk; pk[0] = (_Float16)rv[2*j]; pk[1] = (_Float16)rv[2*j+1];
    rv2[j] = pk;
  }
#endif

  const _Float16* wg = w16 + g * 784;              // uniform -> scalar pipe
#if __has_builtin(__builtin_amdgcn_fdot2)
  const half2v* wg2 = (const half2v*)wg;
#endif
  float acc0 = 0.f, acc1 = 0.f, acc2 = 0.f, acc3 = 0.f;
  #pragma unroll
  for (int kh = 0; kh < 7; kh++){
    #pragma unroll
    for (int kw = 0; kw < 7; kw++){
      int k = kh * 7 + kw;
      float kv0 = 0.f, kv1 = 0.f;                  // split dep chain (2x4 deep)
#if __has_builtin(__builtin_amdgcn_fdot2)
      #pragma unroll
      for (int j = 0; j < 4; j++){
        kv0 = __builtin_amdgcn_fdot2(rv2[j],     wg2[k*8 + j],     kv0, false);
        kv1 = __builtin_amdgcn_fdot2(rv2[j + 4], wg2[k*8 + j + 4], kv1, false);
      }
#else
      #pragma unroll
      for (int c = 0; c < 8; c++){
        kv0 += rv[c]     * (float)wg[k*16 + c];
        kv1 += rv[c + 8] * (float)wg[k*16 + c + 8];
      }
#endif
      float kv = kv0 + kv1;
      float4 hv = s_h4[lty + kh][ltx + kw];
      acc0 += kv * hv.x;
      acc1 += kv * hv.y;
      acc2 += kv * hv.z;
      acc3 += kv * hv.w;
    }
  }

  long obase = (((long)((b << 6) + (g << 2))) << 14) + (py << 7) + px;
  out[obase]         = acc0;
  out[obase + 16384] = acc1;
  out[obase + 32768] = acc2;
  out[obase + 49152] = acc3;
}

extern "C" void kernel_launch(void* const* d_in, const int* in_sizes, int n_in,
                              void* d_out, int out_size, void* d_ws, size_t ws_size,
                              hipStream_t stream){
  const float* in       = (const float*)d_in[0];
  const float* w_dw     = (const float*)d_in[1];
  const float* w_pw     = (const float*)d_in[2];
  const float* gamma    = (const float*)d_in[3];
  const float* beta     = (const float*)d_in[4];
  const float* w_reduce = (const float*)d_in[5];
  const float* w_span   = (const float*)d_in[6];
  float* out = (float*)d_out;

  _Float16* h16 = (_Float16*)d_ws;                 // 4194304 halfs (8 MB)
  _Float16* r16 = h16 + 4194304;                   // 1048576 halfs (2 MB)
  _Float16* w16 = r16 + 1048576;                   // 12544 halfs (pad to 16384)
  float* partial = (float*)(w16 + 16384);          // 1024*32 floats (128 KB)
  float* sb      = partial + 32768;                // 32 floats

  k_front<<<1024, 256, 0, stream>>>(in, w_dw, w_pw, w_reduce, h16, r16, partial);
  k_red  <<<1, 1024, 0, stream>>>(partial, gamma, beta, sb, w_span, w16);
  dim3 grid(64, 16, 4);
  k_main <<<grid, 256, 0, stream>>>(h16, r16, sb, w16, out);
}